// Round 1
// 6975.282 us; speedup vs baseline: 1.3109x; 1.3109x over previous
//
#include <hip/hip_runtime.h>
#include <hip/hip_bf16.h>
#include <stdint.h>

// Problem constants
#define BATCH 32
#define TT    200
#define EDIM  256
#define HDIM  1024
#define VDIM  20000
#define GDIM  4096   // 4*H
#define NWG   256    // persistent grid size

typedef __attribute__((ext_vector_type(8))) short bf16x8;
typedef __attribute__((ext_vector_type(4))) float f32x4;

__device__ __forceinline__ float b2f(unsigned short u) {
  union { float f; uint32_t u; } v; v.u = ((uint32_t)u) << 16; return v.f;
}
__device__ __forceinline__ unsigned short f2b(float f) {
  union { float f; uint32_t u; } v; v.f = f;
  uint32_t u = v.u;
  uint32_t r = u + 0x7fffu + ((u >> 16) & 1u);
  return (unsigned short)(r >> 16);
}
__device__ __forceinline__ float sigf(float x) { return 1.0f / (1.0f + expf(-x)); }

// ---------------- embedding gather: x_bf16[(t*32+b)][e] = emb[ids[b][t]][e] ----------
__global__ void embed_k(const int* __restrict__ ids, const float* __restrict__ emb,
                        unsigned short* __restrict__ xout) {
  int token = blockIdx.x;          // = t*32 + b
  int t = token >> 5, b = token & 31;
  int id = ids[b * TT + t];
  int e = threadIdx.x * 4;
  const float4* src = (const float4*)(emb + (size_t)id * EDIM + e);
  float4 v = *src;
  ushort4 o;
  o.x = f2b(v.x); o.y = f2b(v.y); o.z = f2b(v.z); o.w = f2b(v.w);
  *(ushort4*)(xout + (size_t)token * EDIM + e) = o;
}

// ---------------- fp32 -> bf16 conversion with strided/offset dst (for concat) -------
__global__ void f2b_k(const float* __restrict__ src, unsigned short* __restrict__ dst,
                      int src_cols, int dst_stride, int dst_off) {
  int col = blockIdx.x * 256 + threadIdx.x;
  int row = blockIdx.y;
  dst[(size_t)row * dst_stride + dst_off + col] =
      f2b(src[(size_t)row * src_cols + col]);
}

// ---------------- bias sum: o = a + b ------------------------------------------------
__global__ void bias_k(const float* __restrict__ a, const float* __restrict__ b,
                       float* __restrict__ o) {
  int i = blockIdx.x * 256 + threadIdx.x;
  o[i] = a[i] + b[i];
}

// ---------------- generic NT GEMM: C[MxN] = A[MxK](bf16) * B[NxK](bf16)^T + bias -----
template <bool OUT_BF16, bool N_GUARD>
__global__ __launch_bounds__(256) void gemm_nt(
    const unsigned short* __restrict__ A, const unsigned short* __restrict__ B,
    const float* __restrict__ bias, void* __restrict__ Cv, int M, int N, int K) {
  __shared__ __align__(16) unsigned short lds_a[128 * 40];
  __shared__ __align__(16) unsigned short lds_b[128 * 40];
  int tid = threadIdx.x;
  int wave = tid >> 6, lane = tid & 63;
  int wm = (wave >> 1) * 64, wn = (wave & 1) * 64;
  int m0 = blockIdx.y * 128, n0 = blockIdx.x * 128;
  int lrow = lane & 15, lq = lane >> 4;
  f32x4 acc[4][4] = {};

  for (int k0 = 0; k0 < K; k0 += 32) {
#pragma unroll
    for (int j = 0; j < 2; ++j) {
      int c = tid + j * 256;             // 0..511 chunks of 16B
      int row = c >> 2, seg = c & 3;
      uint4 va = *(const uint4*)(A + (size_t)(m0 + row) * K + k0 + seg * 8);
      *(uint4*)&lds_a[row * 40 + seg * 8] = va;
      uint4 vb = make_uint4(0, 0, 0, 0);
      if (!N_GUARD || (n0 + row) < N)
        vb = *(const uint4*)(B + (size_t)(n0 + row) * K + k0 + seg * 8);
      *(uint4*)&lds_b[row * 40 + seg * 8] = vb;
    }
    __syncthreads();
    bf16x8 af[4], bfr[4];
#pragma unroll
    for (int m = 0; m < 4; ++m)
      af[m] = *(const bf16x8*)&lds_a[(wm + m * 16 + lrow) * 40 + lq * 8];
#pragma unroll
    for (int n = 0; n < 4; ++n)
      bfr[n] = *(const bf16x8*)&lds_b[(wn + n * 16 + lrow) * 40 + lq * 8];
#pragma unroll
    for (int m = 0; m < 4; ++m)
#pragma unroll
      for (int n = 0; n < 4; ++n)
        acc[m][n] = __builtin_amdgcn_mfma_f32_16x16x32_bf16(af[m], bfr[n], acc[m][n], 0, 0, 0);
    __syncthreads();
  }

#pragma unroll
  for (int m = 0; m < 4; ++m) {
    int row = m0 + wm + m * 16 + lq * 4;
#pragma unroll
    for (int n = 0; n < 4; ++n) {
      int col = n0 + wn + n * 16 + lrow;
      if (N_GUARD && col >= N) continue;
      float bv = bias ? bias[col] : 0.0f;
#pragma unroll
      for (int r = 0; r < 4; ++r) {
        float v = acc[m][n][r] + bv;
        size_t idx = (size_t)(row + r) * N + col;
        if (OUT_BF16) ((unsigned short*)Cv)[idx] = f2b(v);
        else          ((float*)Cv)[idx] = v;
      }
    }
  }
}

// ---------------- legacy per-tick kernel (fallback if cooperative launch fails) ------
__global__ __launch_bounds__(256) void lstm_tick(
    int k,
    const unsigned short* __restrict__ state_in,   // 32 x 2048  [h0 | h1] bf16
    unsigned short* __restrict__ state_out,
    float* __restrict__ cbuf,                      // 2 x 32 x 1024 fp32
    const unsigned short* __restrict__ Whh0,       // 4096 x 1024 bf16
    const unsigned short* __restrict__ Wcat1,      // 4096 x 2048 bf16 [Wih1|Whh1]
    const unsigned short* __restrict__ Xg0,        // 6400 x 4096 bf16 (x@Wih0^T + b)
    const float* __restrict__ bias1,               // 4096 (b_ih1+b_hh1)
    const int* __restrict__ lengths,
    unsigned short* __restrict__ outputs) {        // 6400 x 1024 bf16, row = b*200+t
  int layer = blockIdx.x >> 5;
  int slice = blockIdx.x & 31;
  int t = (layer == 0) ? k : (k - 1);
  if (t < 0 || t >= TT) return;

  const unsigned short* W = layer ? Wcat1 : Whh0;
  int Kdim = layer ? 2048 : 1024;
  int tid = threadIdx.x, wave = tid >> 6, lane = tid & 63;
  int lrow = lane & 15, lq = lane >> 4;
  int col0 = slice * 32;

  __shared__ __align__(16) unsigned short lds_s[32 * 72];
  __shared__ float lds_g[4][32][33];

  f32x4 acc[2][2] = {};

  for (int k0 = 0; k0 < Kdim; k0 += 64) {
    {
      int row = tid >> 3, off = (tid & 7) * 8;
      *(uint4*)&lds_s[row * 72 + off] =
          *(const uint4*)(state_in + (size_t)row * 2048 + k0 + off);
    }
    __syncthreads();
#pragma unroll
    for (int kk = 0; kk < 64; kk += 32) {
      bf16x8 af[2], bfr[2];
#pragma unroll
      for (int m = 0; m < 2; ++m)
        af[m] = *(const bf16x8*)&lds_s[(m * 16 + lrow) * 72 + kk + lq * 8];
#pragma unroll
      for (int n = 0; n < 2; ++n) {
        int wrow = wave * 1024 + col0 + n * 16 + lrow;
        bfr[n] = *(const bf16x8*)(W + (size_t)wrow * Kdim + k0 + kk + lq * 8);
      }
#pragma unroll
      for (int m = 0; m < 2; ++m)
#pragma unroll
        for (int n = 0; n < 2; ++n)
          acc[m][n] = __builtin_amdgcn_mfma_f32_16x16x32_bf16(af[m], bfr[n], acc[m][n], 0, 0, 0);
    }
    __syncthreads();
  }

#pragma unroll
  for (int m = 0; m < 2; ++m)
#pragma unroll
    for (int n = 0; n < 2; ++n)
#pragma unroll
      for (int r = 0; r < 4; ++r) {
        int b = m * 16 + lq * 4 + r, c = n * 16 + lrow;
        lds_g[wave][b][c] = acc[m][n][r];
      }
  __syncthreads();

#pragma unroll
  for (int r = 0; r < 4; ++r) {
    int idx = tid * 4 + r;
    int b = idx >> 5, c = idx & 31;
    int col = col0 + c;
    float gi = lds_g[0][b][c], gf = lds_g[1][b][c];
    float gg = lds_g[2][b][c], go = lds_g[3][b][c];
    if (layer == 0) {
      const unsigned short* xg = Xg0 + (size_t)(t * 32 + b) * GDIM;
      gi += b2f(xg[col]);          gf += b2f(xg[1024 + col]);
      gg += b2f(xg[2048 + col]);   go += b2f(xg[3072 + col]);
    } else {
      gi += bias1[col];            gf += bias1[1024 + col];
      gg += bias1[2048 + col];     go += bias1[3072 + col];
    }
    float ig = sigf(gi), fg = sigf(gf), gv = tanhf(gg), og = sigf(go);
    float* cp = cbuf + (size_t)layer * 32768 + b * 1024 + col;
    float cold = *cp;
    float cn = fg * cold + ig * gv;
    float hn = og * tanhf(cn);
    bool msk = (t < lengths[b]);
    if (!msk) {
      cn = cold;
      hn = b2f(state_in[b * 2048 + layer * 1024 + col]);
    }
    *cp = cn;
    state_out[b * 2048 + layer * 1024 + col] = f2b(hn);
    if (layer) outputs[((size_t)b * TT + t) * HDIM + col] = f2b(hn);
  }
}

// ---------------- persistent LSTM: all 201 ticks in one cooperative kernel -----------
// 256 WGs x 512 threads (8 waves). WG wg: layer = wg>>7, slice = wg&127 (8 h-cols,
// 32 gate-rows). Weights pinned in LDS (swizzled), c/h state in registers, h exchanged
// through double-buffered global state with one device-scope barrier per tick.

__device__ __forceinline__ void grid_barrier(unsigned* bar) {
  __syncthreads();   // drains vmcnt: all this-WG global writes are in L2
  if (threadIdx.x == 0) {
    // release (wbl2) -> count arrival -> spin with acquire (inv L1/L2)
    unsigned my = __hip_atomic_fetch_add(bar, 1u, __ATOMIC_ACQ_REL, __HIP_MEMORY_SCOPE_AGENT);
    unsigned target = (my / NWG + 1u) * NWG;
    while (__hip_atomic_load(bar, __ATOMIC_ACQUIRE, __HIP_MEMORY_SCOPE_AGENT) < target)
      __builtin_amdgcn_s_sleep(1);
  }
  __syncthreads();
}

template <int KD, int LAYER>
__device__ __forceinline__ void lstm_body(
    unsigned short* Wl, float (*lds_g)[32][33],
    unsigned short* stateA, unsigned short* stateB,
    const unsigned short* __restrict__ W,        // Whh0 (layer0) or Wcat1 (layer1)
    const unsigned short* __restrict__ Xg0,
    const float* __restrict__ bias1,
    const int* __restrict__ lengths,
    unsigned short* __restrict__ outputs,
    unsigned* bar, int slice) {
  int tid = threadIdx.x;
  int wave = tid >> 6, lane = tid & 63;
  int lrow = lane & 15, lq = lane >> 4;
  int mh = wave & 1, kh = wave >> 1;             // batch-half, K-quarter
  int s8 = slice * 8;

  // ---- preload this WG's 32 weight rows into LDS, XOR-swizzled ----
  constexpr int CPR = KD >> 3;                   // 16B chunks per row
  for (int c = tid; c < 32 * CPR; c += 512) {
    int n = c / CPR;                             // local gate-row 0..31 (= g*8+j)
    int o = (c - n * CPR) * 8;                   // element offset within row
    int grow = ((n >> 3) << 10) + s8 + (n & 7);  // global W row
    uint4 v = *(const uint4*)(W + (size_t)grow * KD + o);
    int byte = ((n * KD + o) << 1) ^ ((n & 7) << 4);
    *(uint4*)((char*)Wl + byte) = v;
  }

  float c_reg = 0.f, h_reg = 0.f;
  float b_i = 0.f, b_f = 0.f, b_g = 0.f, b_o = 0.f;
  int lenb = 0;
  int cb = tid & 31, cj = tid >> 5;              // cell-update (batch, col) for tid<256
  int colh = s8 + cj;
  if (tid < 256) {
    lenb = lengths[cb];
    if (LAYER) {
      b_i = bias1[colh];        b_f = bias1[1024 + colh];
      b_g = bias1[2048 + colh]; b_o = bias1[3072 + colh];
    }
  }
  __syncthreads();

  constexpr int KQ = KD >> 2;                    // K per wave: 256 / 512
  int kbase = kh * KQ;
  int xorv = (lrow & 7) << 4;
  int bb0 = ((lrow * KD + kbase + lq * 8) << 1);
  int bb1 = (((16 + lrow) * KD + kbase + lq * 8) << 1);

  for (int k = 0; k <= TT; ++k) {
    unsigned short* sin  = (k & 1) ? stateB : stateA;
    unsigned short* sout = (k & 1) ? stateA : stateB;
    int t = LAYER ? (k - 1) : k;
    if (t >= 0 && t < TT) {
      // prefetch layer0 input-gate contribution early (hides under GEMM)
      float xgi = 0.f, xgf = 0.f, xgg = 0.f, xgo = 0.f;
      if (!LAYER && tid < 256) {
        const unsigned short* xg = Xg0 + (((size_t)(t * 32 + cb)) << 12) + colh;
        xgi = b2f(xg[0]);    xgf = b2f(xg[1024]);
        xgg = b2f(xg[2048]); xgo = b2f(xg[3072]);
      }
      // GEMM: wave computes a 16(batch) x 32(gate-rows) strip over its K-quarter
      const unsigned short* hp = sin + ((mh * 16 + lrow) << 11) + kbase + lq * 8;
      f32x4 acc0 = {}, acc1 = {};
#pragma unroll
      for (int ks = 0; ks < (KQ >> 5); ++ks) {
        bf16x8 af = *(const bf16x8*)(hp + ks * 32);
        bf16x8 b0 = *(const bf16x8*)((const char*)Wl + ((bb0 + ks * 64) ^ xorv));
        bf16x8 b1 = *(const bf16x8*)((const char*)Wl + ((bb1 + ks * 64) ^ xorv));
        acc0 = __builtin_amdgcn_mfma_f32_16x16x32_bf16(af, b0, acc0, 0, 0, 0);
        acc1 = __builtin_amdgcn_mfma_f32_16x16x32_bf16(af, b1, acc1, 0, 0, 0);
      }
      // exchange partial gate sums (per K-quarter) through LDS
#pragma unroll
      for (int r = 0; r < 4; ++r) {
        lds_g[kh][mh * 16 + lq * 4 + r][lrow]      = acc0[r];
        lds_g[kh][mh * 16 + lq * 4 + r][16 + lrow] = acc1[r];
      }
      __syncthreads();
      if (tid < 256) {
        float gi = lds_g[0][cb][cj]      + lds_g[1][cb][cj]      + lds_g[2][cb][cj]      + lds_g[3][cb][cj];
        float gf = lds_g[0][cb][8 + cj]  + lds_g[1][cb][8 + cj]  + lds_g[2][cb][8 + cj]  + lds_g[3][cb][8 + cj];
        float gg = lds_g[0][cb][16 + cj] + lds_g[1][cb][16 + cj] + lds_g[2][cb][16 + cj] + lds_g[3][cb][16 + cj];
        float go = lds_g[0][cb][24 + cj] + lds_g[1][cb][24 + cj] + lds_g[2][cb][24 + cj] + lds_g[3][cb][24 + cj];
        if (LAYER) { gi += b_i; gf += b_f; gg += b_g; go += b_o; }
        else       { gi += xgi; gf += xgf; gg += xgg; go += xgo; }
        if (t < lenb) {                          // unmasked: update c/h
          float ig = sigf(gi), fg = sigf(gf), gv = tanhf(gg), og = sigf(go);
          c_reg = fg * c_reg + ig * gv;
          h_reg = og * tanhf(c_reg);
        }
        sout[(cb << 11) + (LAYER << 10) + colh] = f2b(h_reg);
        if (LAYER) outputs[(((size_t)(cb * TT + t)) << 10) + colh] = f2b(h_reg);
      }
    } else {
      // pipeline warm-up/drain: still publish carried h (layer1 needs zeros at k=0)
      if (tid < 256)
        sout[(cb << 11) + (LAYER << 10) + colh] = f2b(h_reg);
    }
    grid_barrier(bar);
  }
}

__global__ __launch_bounds__(512) void lstm_persist(
    unsigned short* stateA, unsigned short* stateB,
    const unsigned short* __restrict__ Whh0,
    const unsigned short* __restrict__ Wcat1,
    const unsigned short* __restrict__ Xg0,
    const float* __restrict__ bias1,
    const int* __restrict__ lengths,
    unsigned short* __restrict__ outputs,
    unsigned* bar) {
  __shared__ __align__(16) unsigned short Wl[32 * 2048];   // 128 KiB
  __shared__ float lds_g[4][32][33];                       // 16.5 KiB
  int wg = blockIdx.x;
  if (wg >> 7)
    lstm_body<2048, 1>(Wl, lds_g, stateA, stateB, Wcat1, Xg0, bias1, lengths,
                       outputs, bar, wg & 127);
  else
    lstm_body<1024, 0>(Wl, lds_g, stateA, stateB, Whh0, Xg0, bias1, lengths,
                       outputs, bar, wg & 127);
}

// ---------------- launch ----------------
extern "C" void kernel_launch(void* const* d_in, const int* in_sizes, int n_in,
                              void* d_out, int out_size, void* d_ws, size_t ws_size,
                              hipStream_t stream) {
  const int*   ids    = (const int*)d_in[0];
  const int*   lens   = (const int*)d_in[1];
  const float* emb    = (const float*)d_in[2];
  const float* Wih0   = (const float*)d_in[3];
  const float* Whh0f  = (const float*)d_in[4];
  const float* bih0   = (const float*)d_in[5];
  const float* bhh0   = (const float*)d_in[6];
  const float* Wih1   = (const float*)d_in[7];
  const float* Whh1f  = (const float*)d_in[8];
  const float* bih1   = (const float*)d_in[9];
  const float* bhh1   = (const float*)d_in[10];
  const float* Woutf  = (const float*)d_in[11];
  const float* bout   = (const float*)d_in[12];

  char* ws = (char*)d_ws;
  size_t off = 0;
  auto alloc = [&](size_t bytes) { char* p = ws + off; off += bytes; return p; };
  unsigned short* x_bf   = (unsigned short*)alloc((size_t)6400 * EDIM * 2);
  unsigned short* Xg0    = (unsigned short*)alloc((size_t)6400 * GDIM * 2);
  unsigned short* Wih0b  = (unsigned short*)alloc((size_t)GDIM * EDIM * 2);
  unsigned short* Whh0b  = (unsigned short*)alloc((size_t)GDIM * HDIM * 2);
  unsigned short* Wcat1b = (unsigned short*)alloc((size_t)GDIM * 2048 * 2);
  unsigned short* Woutb  = (unsigned short*)alloc((size_t)VDIM * HDIM * 2);
  unsigned short* outs   = (unsigned short*)alloc((size_t)6400 * HDIM * 2);
  unsigned short* stateA = (unsigned short*)alloc((size_t)BATCH * 2048 * 2);
  unsigned short* stateB = (unsigned short*)alloc((size_t)BATCH * 2048 * 2);
  float*          cbuf   = (float*)alloc((size_t)2 * BATCH * HDIM * 4);
  unsigned*       bar    = (unsigned*)alloc(256);
  float*          bias0s = (float*)alloc(GDIM * 4);
  float*          bias1s = (float*)alloc(GDIM * 4);

  // zero state buffers + cell state + barrier counter (contiguous region)
  hipMemsetAsync(stateA, 0,
                 (size_t)BATCH * 2048 * 2 * 2 + (size_t)2 * BATCH * HDIM * 4 + 256,
                 stream);

  // embed + weight conversions
  embed_k<<<6400, 64, 0, stream>>>(ids, emb, x_bf);
  f2b_k<<<dim3(EDIM / 256, GDIM), 256, 0, stream>>>(Wih0,  Wih0b,  EDIM, EDIM, 0);
  f2b_k<<<dim3(HDIM / 256, GDIM), 256, 0, stream>>>(Whh0f, Whh0b,  HDIM, HDIM, 0);
  f2b_k<<<dim3(HDIM / 256, GDIM), 256, 0, stream>>>(Wih1,  Wcat1b, HDIM, 2048, 0);
  f2b_k<<<dim3(HDIM / 256, GDIM), 256, 0, stream>>>(Whh1f, Wcat1b, HDIM, 2048, 1024);
  f2b_k<<<dim3(HDIM / 256, VDIM), 256, 0, stream>>>(Woutf, Woutb,  HDIM, HDIM, 0);
  bias_k<<<GDIM / 256, 256, 0, stream>>>(bih0, bhh0, bias0s);
  bias_k<<<GDIM / 256, 256, 0, stream>>>(bih1, bhh1, bias1s);

  // Xg0 = x @ Wih0^T + (bih0+bhh0), output bf16   (M=6400, N=4096, K=256)
  gemm_nt<true, false><<<dim3(GDIM / 128, 6400 / 128), 256, 0, stream>>>(
      x_bf, Wih0b, bias0s, Xg0, 6400, GDIM, EDIM);

  // whole recurrence in one persistent cooperative kernel
  {
    void* kargs[] = { (void*)&stateA, (void*)&stateB, (void*)&Whh0b, (void*)&Wcat1b,
                      (void*)&Xg0, (void*)&bias1s, (void*)&lens, (void*)&outs,
                      (void*)&bar };
    hipError_t ce = hipLaunchCooperativeKernel(
        reinterpret_cast<void*>(lstm_persist), dim3(NWG), dim3(512), kargs, 0, stream);
    if (ce != hipSuccess) {
      // fallback: legacy 201-launch pipeline
      for (int k = 0; k <= TT; ++k) {
        const unsigned short* sin = (k & 1) ? stateB : stateA;
        unsigned short* sout      = (k & 1) ? stateA : stateB;
        lstm_tick<<<64, 256, 0, stream>>>(k, sin, sout, cbuf, Whh0b, Wcat1b, Xg0,
                                          bias1s, lens, outs);
      }
    }
  }

  // logits = outputs @ Wout^T + bout   (M=6400, N=20000, K=1024)
  gemm_nt<false, true><<<dim3((VDIM + 127) / 128, 6400 / 128), 256, 0, stream>>>(
      outs, Woutb, bout, (float*)d_out, 6400, VDIM, HDIM);
}